// Round 16
// baseline (42.932 us; speedup 1.0000x reference)
//
#include <hip/hip_runtime.h>
#include <cstdint>

#define P_N 65536
#define G_N 2048
#define L2E 1.4426950408889634f
#define NCELL 512              // 8x8x8 grid
#define BCAP 320               // LDS point capacity per cell (mean 128, sd ~11)
#define CHUNK 256              // records staged per LDS chunk
#define NBLK 256               // eval grid: 1 block/CU, 2 cells per block

#if __has_builtin(__builtin_amdgcn_exp2f)
#define EXP2F __builtin_amdgcn_exp2f
#else
#define EXP2F exp2f
#endif

// ---- ws layout (units: floats/ints, 4B each) ----
#define OFF_FLAG 0
#define OFF_PAR  64
#define OFF_MU   (OFF_PAR + (G_N + 2) * 16)   // float4 (mu.xyz, r2)
#define NEED_FLOATS (OFF_MU + G_N * 4)        // ~165 KB

__device__ __forceinline__ float sigmoidf(float x) {
    return 1.0f / (1.0f + expf(-x));
}

// params: [0..8] M = sqrt(L2E/2)*diag(1/s)*R^T, [9..11] nb=-M·mu, [12] lw, pad
// grid = 9 blocks: 0..7 compute records; block 8 does init work
__global__ __launch_bounds__(256) void precompute_kernel(
        const float* __restrict__ xyz,
        const float* __restrict__ weight,
        const float* __restrict__ scaling,
        const float* __restrict__ rotation,
        const float* __restrict__ values,
        const uint8_t* __restrict__ inside_raw,
        float* __restrict__ ws, int aux) {
    if (blockIdx.x == 8) {
        __shared__ int s_nz;
        if (threadIdx.x == 0) s_nz = 0;
        __syncthreads();
        int nz = 0;
        for (int i = threadIdx.x; i < 4096; i += blockDim.x) {
            if ((i & 3) != 0 && inside_raw[i] != 0) nz = 1;
        }
        if (nz) atomicOr(&s_nz, 1);
        __syncthreads();
        if (threadIdx.x == 0) ((int*)ws)[OFF_FLAG] = s_nz;
        if (threadIdx.x < 32) ws[OFF_PAR + (size_t)G_N * 16 + threadIdx.x] = 0.0f;
        return;
    }

    int g = blockIdx.x * blockDim.x + threadIdx.x;
    if (g >= G_N) return;

    float s0 = expf(scaling[3 * g + 0]);
    float s1 = expf(scaling[3 * g + 1]);
    float s2 = expf(scaling[3 * g + 2]);
    float r = sqrtf(s0 * s0 + s1 * s1 + s2 * s2) + 1e-8f;
    float r_soft = 0.02f * tanhf(r / 0.02f);
    float f = r_soft / r;
    s0 *= f; s1 *= f; s2 *= f;

    float qw = rotation[4 * g + 0], qx = rotation[4 * g + 1];
    float qy = rotation[4 * g + 2], qz = rotation[4 * g + 3];
    float qn = sqrtf(qw * qw + qx * qx + qy * qy + qz * qz) + 1e-12f;
    qw /= qn; qx /= qn; qy /= qn; qz /= qn;
    float r00 = 1.0f - 2.0f * (qy * qy + qz * qz);
    float r01 = 2.0f * (qx * qy - qw * qz);
    float r02 = 2.0f * (qx * qz + qw * qy);
    float r10 = 2.0f * (qx * qy + qw * qz);
    float r11 = 1.0f - 2.0f * (qx * qx + qz * qz);
    float r12 = 2.0f * (qy * qz - qw * qx);
    float r20 = 2.0f * (qx * qz - qw * qy);
    float r21 = 2.0f * (qy * qz + qw * qx);
    float r22 = 1.0f - 2.0f * (qx * qx + qy * qy);

    const float k = 0.84932180028801904f;  // sqrt(L2E*0.5)
    float k0 = k / s0, k1 = k / s1, k2 = k / s2;
    float m00 = k0 * r00, m01 = k0 * r10, m02 = k0 * r20;
    float m10 = k1 * r01, m11 = k1 * r11, m12 = k1 * r21;
    float m20 = k2 * r02, m21 = k2 * r12, m22 = k2 * r22;

    float mx = xyz[3 * g + 0], my = xyz[3 * g + 1], mz = xyz[3 * g + 2];
    float wv = sigmoidf(weight[g]) * sigmoidf(values[g]);

    float* c = ws + OFF_PAR + (size_t)g * 16;
    c[0] = m00; c[1] = m01; c[2] = m02;
    c[3] = m10; c[4] = m11; c[5] = m12;
    c[6] = m20; c[7] = m21; c[8] = m22;
    c[9]  = -(m00 * mx + m01 * my + m02 * mz);
    c[10] = -(m10 * mx + m11 * my + m12 * mz);
    c[11] = -(m20 * mx + m21 * my + m22 * mz);
    c[12] = log2f(wv);
    c[13] = 0.0f; c[14] = 0.0f; c[15] = 0.0f;

    if (aux) {
        // keep iff dist2(mu, cellbox) < 40*smax^2  (term bound 2^-28.8)
        float smax = fmaxf(s0, fmaxf(s1, s2));
        ((float4*)(ws + OFF_MU))[g] = make_float4(mx, my, mz, 40.0f * smax * smax);
    }
}

// record applied to one point; record in float4 regs r0..r3
#define GPOINT(r0, r1, r2, r3, Xk, Yk, Zk, acck)                              \
    {                                                                         \
        float u0 = fmaf(r0.x, Xk, fmaf(r0.y, Yk, fmaf(r0.z, Zk, r2.y)));      \
        float u1 = fmaf(r0.w, Xk, fmaf(r1.x, Yk, fmaf(r1.y, Zk, r2.z)));      \
        float u2 = fmaf(r1.z, Xk, fmaf(r1.w, Yk, fmaf(r2.x, Zk, r2.w)));      \
        float tt = fmaf(-u0, u0, r3.x);                                       \
        tt = fmaf(-u1, u1, tt);                                               \
        tt = fmaf(-u2, u2, tt);                                               \
        acck += EXP2F(tt);                                                    \
    }

// sync-free fused eval: each block streams ALL points (L2-resident, 768 KB)
// via float4 loads (3 per 4 points), conditional LDS atomics on hits only,
// then evals its 2 cells with the round-11 PT=2 ping-pong shape.
__global__ __launch_bounds__(512) void eval_filter_kernel(
        const float* __restrict__ x,
        const float* __restrict__ ws,
        const void* __restrict__ inside,
        float* __restrict__ out) {
    __shared__ int    slist[G_N];          // 8 KB
    __shared__ float4 sbuf[CHUNK * 4];     // 16 KB
    __shared__ float4 spts[2][BCAP];       // 10 KB
    __shared__ float  comb[4][256];        // 4 KB
    __shared__ int    spcnt[2];
    __shared__ int    scnt;

    const int t = threadIdx.x;
    const int lane = t & 63;
    const int c0 = blockIdx.x * 2;         // this block's two cells

    const int mode = ((const int*)ws)[OFF_FLAG];
    const float4* mu4  = (const float4*)(ws + OFF_MU);
    const float4* par4 = (const float4*)(ws + OFF_PAR);
    const float4* xv4  = (const float4*)x;

    if (t < 2) spcnt[t] = 0;
    __syncthreads();

    // ---- phase A: stream all points; 2 quads (8 points) = 6 float4 loads
    //      per thread per iteration; LDS atomic only on a hit (~256/blk) ----
#define PPROC(PX, PY, PZ, PP)                                                 \
    {                                                                         \
        float X = (PX + 1.0f) * 0.5f;                                         \
        float Y = (PY + 1.0f) * 0.5f;                                         \
        float Z = (PZ + 1.0f) * 0.5f;                                         \
        int cx = min(7, max(0, (int)(X * 8.0f)));                             \
        int cy = min(7, max(0, (int)(Y * 8.0f)));                             \
        int cz = min(7, max(0, (int)(Z * 8.0f)));                             \
        int cell = cx + 8 * cy + 64 * cz;                                     \
        if (cell == c0) {                                                     \
            int idx = atomicAdd(&spcnt[0], 1);                                \
            if (idx < BCAP)                                                   \
                spts[0][idx] = make_float4(X, Y, Z, __int_as_float(PP));      \
        } else if (cell == c0 + 1) {                                          \
            int idx = atomicAdd(&spcnt[1], 1);                                \
            if (idx < BCAP)                                                   \
                spts[1][idx] = make_float4(X, Y, Z, __int_as_float(PP));      \
        }                                                                     \
    }

#pragma unroll 1
    for (int base = 0; base < P_N / 4; base += 1024) {
        int qa = base + t;                 // quad A: points 4qa..4qa+3
        int qb = qa + 512;                 // quad B
        float4 a0 = xv4[3 * qa + 0];
        float4 a1 = xv4[3 * qa + 1];
        float4 a2 = xv4[3 * qa + 2];
        float4 b0 = xv4[3 * qb + 0];
        float4 b1 = xv4[3 * qb + 1];
        float4 b2 = xv4[3 * qb + 2];
        PPROC(a0.x, a0.y, a0.z, 4 * qa + 0);
        PPROC(a0.w, a1.x, a1.y, 4 * qa + 1);
        PPROC(a1.z, a1.w, a2.x, 4 * qa + 2);
        PPROC(a2.y, a2.z, a2.w, 4 * qa + 3);
        PPROC(b0.x, b0.y, b0.z, 4 * qb + 0);
        PPROC(b0.w, b1.x, b1.y, 4 * qb + 1);
        PPROC(b1.z, b1.w, b2.x, 4 * qb + 2);
        PPROC(b2.y, b2.z, b2.w, 4 * qb + 3);
    }
#undef PPROC
    __syncthreads();

    const unsigned long long lmask =
        (lane == 63) ? ~0ull : ((1ull << (lane + 1)) - 1ull);
    const int q    = t & 3;    // record lane-group (every 4th record)
    const int pair = t >> 2;   // 0..127 -> 2 adjacent points

    // ---- phase B: eval each cell with round-11 PT=2 ping-pong ----
    for (int s = 0; s < 2; ++s) {
        const int c = c0 + s;
        int npts = min(spcnt[s], BCAP);
        __syncthreads();                   // guard slist/sbuf/comb reuse
        if (t == 0) scnt = 0;
        __syncthreads();
        if (npts == 0) continue;

        const int cx = c & 7, cy = (c >> 3) & 7, cz = c >> 6;
        const float bnx = cx * 0.125f, bxx = bnx + 0.125f;
        const float bny = cy * 0.125f, bxy = bny + 0.125f;
        const float bnz = cz * 0.125f, bxz = bnz + 0.125f;

        // ballot-compacted active record list (1 LDS atomic/wave/round)
#pragma unroll
        for (int i = 0; i < G_N / 512; ++i) {
            int g = t + 512 * i;
            float4 m = mu4[g];
            float dx = fmaxf(fmaxf(bnx - m.x, m.x - bxx), 0.0f);
            float dy = fmaxf(fmaxf(bny - m.y, m.y - bxy), 0.0f);
            float dz = fmaxf(fmaxf(bnz - m.z, m.z - bxz), 0.0f);
            float d2 = dx * dx + dy * dy + dz * dz;
            bool keep = d2 < m.w;
            unsigned long long mask = __ballot(keep);
            int nk = __popcll(mask);
            int pref = __popcll(mask & lmask) - (keep ? 1 : 0);
            int base = 0;
            if (lane == 0) base = atomicAdd(&scnt, nk);
            base = __shfl(base, 0);
            if (keep) slist[base + pref] = g;
        }
        __syncthreads();
        const int cnt = scnt;

        for (int pbase = 0; pbase < npts; pbase += 256) {
            __syncthreads();               // comb reuse guard across batches
            int lp0 = 2 * pair, lp1 = lp0 + 1;
            int gp0 = pbase + lp0, gp1 = pbase + lp1;
            bool v0 = gp0 < npts, v1 = gp1 < npts;
            float4 ptA = spts[s][v0 ? gp0 : 0];
            float4 ptB = spts[s][v1 ? gp1 : 0];
            float X0 = ptA.x, Y0 = ptA.y, Z0 = ptA.z;
            float X1 = ptB.x, Y1 = ptB.y, Z1 = ptB.z;
            float a0 = 0.0f, a1 = 0.0f;

            for (int cb = 0; cb < cnt; cb += CHUNK) {
                int cn = min(CHUNK, cnt - cb);
                __syncthreads();
                for (int idx = t; idx < cn * 4; idx += 512) {
                    int g = slist[cb + (idx >> 2)];
                    sbuf[idx] = par4[(size_t)g * 4 + (idx & 3)];
                }
                __syncthreads();
                if (v0) {                  // whole-wave skip for invalid range
                    int ia = min(q, cn - 1);
                    float4 A0 = sbuf[ia * 4 + 0], A1 = sbuf[ia * 4 + 1];
                    float4 A2 = sbuf[ia * 4 + 2], A3 = sbuf[ia * 4 + 3];
#pragma unroll 1
                    for (int j = q; j < cn; j += 4) {
                        int ib = min(j + 4, cn - 1);   // clamped prefetch
                        float4 B0 = sbuf[ib * 4 + 0], B1 = sbuf[ib * 4 + 1];
                        float4 B2 = sbuf[ib * 4 + 2], B3 = sbuf[ib * 4 + 3];
                        GPOINT(A0, A1, A2, A3, X0, Y0, Z0, a0);
                        GPOINT(A0, A1, A2, A3, X1, Y1, Z1, a1);
                        A0 = B0; A1 = B1; A2 = B2; A3 = B3;
                    }
                }
            }

            __syncthreads();
            comb[q][lp0] = v0 ? a0 : 0.0f;
            comb[q][lp1] = v1 ? a1 : 0.0f;
            __syncthreads();
            if (t < 256) {
                int gp = pbase + t;
                if (gp < npts) {
                    float y = comb[0][t] + comb[1][t] + comb[2][t] + comb[3][t];
                    float4 pt = spts[s][gp];
                    int p = __float_as_int(pt.w);
                    bool m = mode ? (((const uint8_t*)inside)[p] != 0)
                                  : (((const int*)inside)[p] != 0);
                    out[p] = m ? y : 0.0f; // every point stored exactly once
                }
            }
        }
    }
}

// ---------- fallback for small ws (round-6 path) ----------
__global__ __launch_bounds__(256) void zero_out_kernel(float* __restrict__ out) {
    out[blockIdx.x * 256 + threadIdx.x] = 0.0f;
}

#define GAUSS_REC4(r0, r1, r2, r3)                                            \
    GPOINT(r0, r1, r2, r3, X0, Y0, Z0, acc0);                                 \
    GPOINT(r0, r1, r2, r3, X1, Y1, Z1, acc1);                                 \
    GPOINT(r0, r1, r2, r3, X2, Y2, Z2, acc2);                                 \
    GPOINT(r0, r1, r2, r3, X3, Y3, Z3, acc3);

__global__ __launch_bounds__(256) void eval_kernel(
        const float* __restrict__ x,
        const float* __restrict__ ws,
        const void* __restrict__ inside,
        float* __restrict__ out) {
    __shared__ float4 spbuf[1028];
    const float* params = ws + OFF_PAR;
    const int mode = ((const int*)ws)[OFF_FLAG];
    const int tid = threadIdx.x, lane = tid & 63, w = tid >> 6;
    const int segq = blockIdx.x & 7, pg = blockIdx.x >> 3;

    const float4* src = (const float4*)(params + (size_t)segq * 256 * 16);
#pragma unroll
    for (int i = 0; i < 4; ++i) spbuf[tid + 256 * i] = src[tid + 256 * i];
    if (tid < 4) spbuf[1024 + tid] = src[1024 + tid];

    const int p0 = pg * 256 + lane;
    float X0 = (x[3 * (p0 + 0) + 0] + 1.0f) * 0.5f;
    float Y0 = (x[3 * (p0 + 0) + 1] + 1.0f) * 0.5f;
    float Z0 = (x[3 * (p0 + 0) + 2] + 1.0f) * 0.5f;
    float X1 = (x[3 * (p0 + 64) + 0] + 1.0f) * 0.5f;
    float Y1 = (x[3 * (p0 + 64) + 1] + 1.0f) * 0.5f;
    float Z1 = (x[3 * (p0 + 64) + 2] + 1.0f) * 0.5f;
    float X2 = (x[3 * (p0 + 128) + 0] + 1.0f) * 0.5f;
    float Y2 = (x[3 * (p0 + 128) + 1] + 1.0f) * 0.5f;
    float Z2 = (x[3 * (p0 + 128) + 2] + 1.0f) * 0.5f;
    float X3 = (x[3 * (p0 + 192) + 0] + 1.0f) * 0.5f;
    float Y3 = (x[3 * (p0 + 192) + 1] + 1.0f) * 0.5f;
    float Z3 = (x[3 * (p0 + 192) + 2] + 1.0f) * 0.5f;
    __syncthreads();

    const float4* sp = spbuf + (size_t)w * 256;
    float acc0 = 0, acc1 = 0, acc2 = 0, acc3 = 0;
    float4 A0 = sp[0], A1 = sp[1], A2 = sp[2], A3 = sp[3];
    float4 B0, B1, B2, B3;
#pragma unroll 1
    for (int g = 0; g < 64; g += 2) {
        const float4* qq = sp + (size_t)(g + 1) * 4;
        B0 = qq[0]; B1 = qq[1]; B2 = qq[2]; B3 = qq[3];
        GAUSS_REC4(A0, A1, A2, A3);
        qq = sp + (size_t)(g + 2) * 4;
        A0 = qq[0]; A1 = qq[1]; A2 = qq[2]; A3 = qq[3];
        GAUSS_REC4(B0, B1, B2, B3);
    }
    __syncthreads();
    float* part = (float*)spbuf;
    part[w * 256 + 0 + lane] = acc0;
    part[w * 256 + 64 + lane] = acc1;
    part[w * 256 + 128 + lane] = acc2;
    part[w * 256 + 192 + lane] = acc3;
    __syncthreads();
    float y = part[tid] + part[256 + tid] + part[512 + tid] + part[768 + tid];
    int p = pg * 256 + tid;
    bool m = mode ? (((const uint8_t*)inside)[p] != 0)
                  : (((const int*)inside)[p] != 0);
    if (m) atomicAdd(&out[p], y);
}

extern "C" void kernel_launch(void* const* d_in, const int* in_sizes, int n_in,
                              void* d_out, int out_size, void* d_ws, size_t ws_size,
                              hipStream_t stream) {
    const float* x        = (const float*)d_in[0];
    const float* xyz      = (const float*)d_in[1];
    const float* weight   = (const float*)d_in[2];
    const float* scaling  = (const float*)d_in[3];
    const float* rotation = (const float*)d_in[4];
    const float* values   = (const float*)d_in[5];
    const void*  inside   = d_in[6];

    float* ws = (float*)d_ws;

    if (ws_size >= (size_t)NEED_FLOATS * 4) {
        precompute_kernel<<<9, 256, 0, stream>>>(
            xyz, weight, scaling, rotation, values, (const uint8_t*)inside, ws, 1);
        eval_filter_kernel<<<NBLK, 512, 0, stream>>>(
            x, ws, inside, (float*)d_out);
    } else if (ws_size >= (size_t)(256 + (G_N + 2) * 16 * 4)) {
        zero_out_kernel<<<P_N / 256, 256, 0, stream>>>((float*)d_out);
        precompute_kernel<<<9, 256, 0, stream>>>(
            xyz, weight, scaling, rotation, values, (const uint8_t*)inside, ws, 0);
        eval_kernel<<<(P_N / 256) * 8, 256, 0, stream>>>(
            x, ws, inside, (float*)d_out);
    }
}

// Round 17
// 18.750 us; speedup vs baseline: 2.2897x; 2.2897x over previous
//
#include <hip/hip_runtime.h>
#include <cstdint>

#define P_N 65536
#define G_N 2048
#define L2E 1.4426950408889634f
#define NCELL 512              // 8x8x8 grid
#define BCAP 320               // LDS point capacity per cell
#define CHUNK 256              // records staged per LDS chunk
#define SCAT_B 128             // scatter blocks (512 points each)
#define CAP 20                 // slots per (cell, scatter-block); Poisson(1)

#if __has_builtin(__builtin_amdgcn_exp2f)
#define EXP2F __builtin_amdgcn_exp2f
#else
#define EXP2F exp2f
#endif

// ---- ws layout (units: floats/ints, 4B each) ----
#define OFF_FLAG 0
#define OFF_PAR  64
#define OFF_MU   (OFF_PAR + (G_N + 2) * 16)     // float4 (mu.xyz, r2)
#define OFF_CNT  (OFF_MU + G_N * 4)             // count[c][b]: NCELL*SCAT_B ints
#define OFF_SLOT (OFF_CNT + NCELL * SCAT_B)     // NCELL*SCAT_B*CAP float4
#define NEED_FLOATS (OFF_SLOT + (size_t)NCELL * SCAT_B * CAP * 4)  // ~21.4 MB

__device__ __forceinline__ float sigmoidf(float x) {
    return 1.0f / (1.0f + expf(-x));
}

// ---- K_A: one dispatch = scatter (blocks 0..127) + precompute (128..131)
//      + dtype detect / pad zero (block 132). No inter-block dependencies.
__global__ __launch_bounds__(512) void prep_kernel(
        const float* __restrict__ x,
        const float* __restrict__ xyz,
        const float* __restrict__ weight,
        const float* __restrict__ scaling,
        const float* __restrict__ rotation,
        const float* __restrict__ values,
        const uint8_t* __restrict__ inside_raw,
        float* __restrict__ ws) {
    const int bid = blockIdx.x;
    const int t = threadIdx.x;

    if (bid < SCAT_B) {
        // ---- scatter: 512 consecutive points into private sub-buckets ----
        __shared__ int hcnt[NCELL];
        for (int i = t; i < NCELL; i += 512) hcnt[i] = 0;
        __syncthreads();
        int p = bid * 512 + t;
        float X = (x[3 * p + 0] + 1.0f) * 0.5f;
        float Y = (x[3 * p + 1] + 1.0f) * 0.5f;
        float Z = (x[3 * p + 2] + 1.0f) * 0.5f;
        int cx = min(7, max(0, (int)(X * 8.0f)));
        int cy = min(7, max(0, (int)(Y * 8.0f)));
        int cz = min(7, max(0, (int)(Z * 8.0f)));
        int cell = cx + 8 * cy + 64 * cz;
        int k = atomicAdd(&hcnt[cell], 1);
        if (k < CAP)
            ((float4*)(ws + OFF_SLOT))[((size_t)cell * SCAT_B + bid) * CAP + k] =
                make_float4(X, Y, Z, __int_as_float(p));
        __syncthreads();
        for (int i = t; i < NCELL; i += 512)
            ((int*)ws)[OFF_CNT + i * SCAT_B + bid] = min(hcnt[i], CAP);
        return;
    }

    if (bid == SCAT_B + 4) {
        // ---- dtype detect + pad records ----
        __shared__ int s_nz;
        if (t == 0) s_nz = 0;
        __syncthreads();
        int nz = 0;
        for (int i = t; i < 4096; i += 512) {
            if ((i & 3) != 0 && inside_raw[i] != 0) nz = 1;
        }
        if (nz) atomicOr(&s_nz, 1);
        __syncthreads();
        if (t == 0) ((int*)ws)[OFF_FLAG] = s_nz;
        if (t < 32) ws[OFF_PAR + (size_t)G_N * 16 + t] = 0.0f;
        return;
    }

    // ---- precompute: g in [ (bid-SCAT_B)*512, ... ) ----
    int g = (bid - SCAT_B) * 512 + t;
    if (g >= G_N) return;

    float s0 = expf(scaling[3 * g + 0]);
    float s1 = expf(scaling[3 * g + 1]);
    float s2 = expf(scaling[3 * g + 2]);
    float r = sqrtf(s0 * s0 + s1 * s1 + s2 * s2) + 1e-8f;
    float r_soft = 0.02f * tanhf(r / 0.02f);
    float f = r_soft / r;
    s0 *= f; s1 *= f; s2 *= f;

    float qw = rotation[4 * g + 0], qx = rotation[4 * g + 1];
    float qy = rotation[4 * g + 2], qz = rotation[4 * g + 3];
    float qn = sqrtf(qw * qw + qx * qx + qy * qy + qz * qz) + 1e-12f;
    qw /= qn; qx /= qn; qy /= qn; qz /= qn;
    float r00 = 1.0f - 2.0f * (qy * qy + qz * qz);
    float r01 = 2.0f * (qx * qy - qw * qz);
    float r02 = 2.0f * (qx * qz + qw * qy);
    float r10 = 2.0f * (qx * qy + qw * qz);
    float r11 = 1.0f - 2.0f * (qx * qx + qz * qz);
    float r12 = 2.0f * (qy * qz - qw * qx);
    float r20 = 2.0f * (qx * qz - qw * qy);
    float r21 = 2.0f * (qy * qz + qw * qx);
    float r22 = 1.0f - 2.0f * (qx * qx + qy * qy);

    const float k = 0.84932180028801904f;  // sqrt(L2E*0.5)
    float k0 = k / s0, k1 = k / s1, k2 = k / s2;
    float m00 = k0 * r00, m01 = k0 * r10, m02 = k0 * r20;
    float m10 = k1 * r01, m11 = k1 * r11, m12 = k1 * r21;
    float m20 = k2 * r02, m21 = k2 * r12, m22 = k2 * r22;

    float mx = xyz[3 * g + 0], my = xyz[3 * g + 1], mz = xyz[3 * g + 2];
    float wv = sigmoidf(weight[g]) * sigmoidf(values[g]);

    float* c = ws + OFF_PAR + (size_t)g * 16;
    c[0] = m00; c[1] = m01; c[2] = m02;
    c[3] = m10; c[4] = m11; c[5] = m12;
    c[6] = m20; c[7] = m21; c[8] = m22;
    c[9]  = -(m00 * mx + m01 * my + m02 * mz);
    c[10] = -(m10 * mx + m11 * my + m12 * mz);
    c[11] = -(m20 * mx + m21 * my + m22 * mz);
    c[12] = log2f(wv);
    c[13] = 0.0f; c[14] = 0.0f; c[15] = 0.0f;

    // keep iff dist2(mu, cellbox) < 40*smax^2  (term bound 2^-28.8)
    float smax = fmaxf(s0, fmaxf(s1, s2));
    ((float4*)(ws + OFF_MU))[g] = make_float4(mx, my, mz, 40.0f * smax * smax);
}

// record applied to one point; record in float4 regs r0..r3
#define GPOINT(r0, r1, r2, r3, Xk, Yk, Zk, acck)                              \
    {                                                                         \
        float u0 = fmaf(r0.x, Xk, fmaf(r0.y, Yk, fmaf(r0.z, Zk, r2.y)));      \
        float u1 = fmaf(r0.w, Xk, fmaf(r1.x, Yk, fmaf(r1.y, Zk, r2.z)));      \
        float u2 = fmaf(r1.z, Xk, fmaf(r1.w, Yk, fmaf(r2.x, Zk, r2.w)));      \
        float tt = fmaf(-u0, u0, r3.x);                                       \
        tt = fmaf(-u1, u1, tt);                                               \
        tt = fmaf(-u2, u2, tt);                                               \
        acck += EXP2F(tt);                                                    \
    }

// ---- K_B: one block per cell. Gather points from the 128 sub-buckets via
//      deterministic 2-wave shuffle prefix, then round-11 list+ping-pong eval.
__global__ __launch_bounds__(512) void eval_cell_kernel(
        const float* __restrict__ ws,
        const void* __restrict__ inside,
        float* __restrict__ out) {
    __shared__ int    slist[G_N];          // 8 KB
    __shared__ float4 sbuf[CHUNK * 4];     // 16 KB
    __shared__ float4 spts[BCAP];          // 5 KB
    __shared__ float  comb[4][256];        // 4 KB
    __shared__ int    scnt, wtot[2];

    const int c = blockIdx.x;
    const int t = threadIdx.x;
    const int lane = t & 63;
    const int mode = ((const int*)ws)[OFF_FLAG];

    // ---- gather: threads 0..127 each own one scatter-block's sub-bucket ----
    int cnt_b = 0, excl = 0;
    if (t < SCAT_B) {
        cnt_b = min(((const int*)ws)[OFF_CNT + c * SCAT_B + t], CAP);
        int incl = cnt_b;
#pragma unroll
        for (int d = 1; d < 64; d <<= 1) {
            int v = __shfl_up(incl, (unsigned)d);
            if (lane >= d) incl += v;
        }
        excl = incl - cnt_b;
        if (lane == 63) wtot[t >> 6] = incl;
    }
    if (t == 0) scnt = 0;
    __syncthreads();
    const int npts = min(wtot[0] + wtot[1], BCAP);
    if (npts == 0) return;
    if (t < SCAT_B && cnt_b > 0) {
        int base = excl + ((t >= 64) ? wtot[0] : 0);
        const float4* sl = (const float4*)(ws + OFF_SLOT) +
                           ((size_t)c * SCAT_B + t) * CAP;
        for (int k = 0; k < cnt_b; ++k) {
            int idx = base + k;
            if (idx < BCAP) spts[idx] = sl[k];
        }
    }

    // ---- ballot-compacted active record list ----
    const float4* mu4  = (const float4*)(ws + OFF_MU);
    const float4* par4 = (const float4*)(ws + OFF_PAR);
    const int cx = c & 7, cy = (c >> 3) & 7, cz = c >> 6;
    const float bnx = cx * 0.125f, bxx = bnx + 0.125f;
    const float bny = cy * 0.125f, bxy = bny + 0.125f;
    const float bnz = cz * 0.125f, bxz = bnz + 0.125f;
    const unsigned long long lmask =
        (lane == 63) ? ~0ull : ((1ull << (lane + 1)) - 1ull);
#pragma unroll
    for (int i = 0; i < G_N / 512; ++i) {
        int g = t + 512 * i;
        float4 m = mu4[g];
        float dx = fmaxf(fmaxf(bnx - m.x, m.x - bxx), 0.0f);
        float dy = fmaxf(fmaxf(bny - m.y, m.y - bxy), 0.0f);
        float dz = fmaxf(fmaxf(bnz - m.z, m.z - bxz), 0.0f);
        float d2 = dx * dx + dy * dy + dz * dz;
        bool keep = d2 < m.w;
        unsigned long long mask = __ballot(keep);
        int nk = __popcll(mask);
        int pref = __popcll(mask & lmask) - (keep ? 1 : 0);
        int base = 0;
        if (lane == 0) base = atomicAdd(&scnt, nk);
        base = __shfl(base, 0);
        if (keep) slist[base + pref] = g;
    }
    __syncthreads();   // spts + slist both ready
    const int cnt = scnt;

    const int q    = t & 3;    // record lane-group (every 4th record)
    const int pair = t >> 2;   // 0..127 -> 2 adjacent points

    for (int pbase = 0; pbase < npts; pbase += 256) {
        __syncthreads();       // comb reuse guard across batches
        int lp0 = 2 * pair, lp1 = lp0 + 1;
        int gp0 = pbase + lp0, gp1 = pbase + lp1;
        bool v0 = gp0 < npts, v1 = gp1 < npts;
        float4 ptA = spts[v0 ? gp0 : 0];
        float4 ptB = spts[v1 ? gp1 : 0];
        float X0 = ptA.x, Y0 = ptA.y, Z0 = ptA.z;
        float X1 = ptB.x, Y1 = ptB.y, Z1 = ptB.z;
        float a0 = 0.0f, a1 = 0.0f;

        for (int cb = 0; cb < cnt; cb += CHUNK) {
            int cn = min(CHUNK, cnt - cb);
            __syncthreads();
            for (int idx = t; idx < cn * 4; idx += 512) {
                int g = slist[cb + (idx >> 2)];
                sbuf[idx] = par4[(size_t)g * 4 + (idx & 3)];
            }
            __syncthreads();
            if (v0) {          // whole-wave skip for invalid point range
                int ia = min(q, cn - 1);
                float4 A0 = sbuf[ia * 4 + 0], A1 = sbuf[ia * 4 + 1];
                float4 A2 = sbuf[ia * 4 + 2], A3 = sbuf[ia * 4 + 3];
#pragma unroll 1
                for (int j = q; j < cn; j += 4) {
                    int ib = min(j + 4, cn - 1);   // clamped prefetch
                    float4 B0 = sbuf[ib * 4 + 0], B1 = sbuf[ib * 4 + 1];
                    float4 B2 = sbuf[ib * 4 + 2], B3 = sbuf[ib * 4 + 3];
                    GPOINT(A0, A1, A2, A3, X0, Y0, Z0, a0);
                    GPOINT(A0, A1, A2, A3, X1, Y1, Z1, a1);
                    A0 = B0; A1 = B1; A2 = B2; A3 = B3;
                }
            }
        }

        __syncthreads();
        comb[q][lp0] = v0 ? a0 : 0.0f;
        comb[q][lp1] = v1 ? a1 : 0.0f;
        __syncthreads();
        if (t < 256) {
            int gp = pbase + t;
            if (gp < npts) {
                float y = comb[0][t] + comb[1][t] + comb[2][t] + comb[3][t];
                float4 pt = spts[gp];
                int p = __float_as_int(pt.w);
                bool m = mode ? (((const uint8_t*)inside)[p] != 0)
                              : (((const int*)inside)[p] != 0);
                out[p] = m ? y : 0.0f;   // every point stored exactly once
            }
        }
    }
}

// ---------- fallback for small ws (round-6 path) ----------
__global__ __launch_bounds__(256) void zero_out_kernel(float* __restrict__ out) {
    out[blockIdx.x * 256 + threadIdx.x] = 0.0f;
}

__global__ __launch_bounds__(256) void precompute_kernel(
        const float* __restrict__ xyz,
        const float* __restrict__ weight,
        const float* __restrict__ scaling,
        const float* __restrict__ rotation,
        const float* __restrict__ values,
        const uint8_t* __restrict__ inside_raw,
        float* __restrict__ ws) {
    if (blockIdx.x == 8) {
        __shared__ int s_nz;
        if (threadIdx.x == 0) s_nz = 0;
        __syncthreads();
        int nz = 0;
        for (int i = threadIdx.x; i < 4096; i += blockDim.x) {
            if ((i & 3) != 0 && inside_raw[i] != 0) nz = 1;
        }
        if (nz) atomicOr(&s_nz, 1);
        __syncthreads();
        if (threadIdx.x == 0) ((int*)ws)[OFF_FLAG] = s_nz;
        if (threadIdx.x < 32) ws[OFF_PAR + (size_t)G_N * 16 + threadIdx.x] = 0.0f;
        return;
    }
    int g = blockIdx.x * blockDim.x + threadIdx.x;
    if (g >= G_N) return;
    float s0 = expf(scaling[3 * g + 0]);
    float s1 = expf(scaling[3 * g + 1]);
    float s2 = expf(scaling[3 * g + 2]);
    float r = sqrtf(s0 * s0 + s1 * s1 + s2 * s2) + 1e-8f;
    float r_soft = 0.02f * tanhf(r / 0.02f);
    float f = r_soft / r;
    s0 *= f; s1 *= f; s2 *= f;
    float qw = rotation[4 * g + 0], qx = rotation[4 * g + 1];
    float qy = rotation[4 * g + 2], qz = rotation[4 * g + 3];
    float qn = sqrtf(qw * qw + qx * qx + qy * qy + qz * qz) + 1e-12f;
    qw /= qn; qx /= qn; qy /= qn; qz /= qn;
    float r00 = 1.0f - 2.0f * (qy * qy + qz * qz);
    float r01 = 2.0f * (qx * qy - qw * qz);
    float r02 = 2.0f * (qx * qz + qw * qy);
    float r10 = 2.0f * (qx * qy + qw * qz);
    float r11 = 1.0f - 2.0f * (qx * qx + qz * qz);
    float r12 = 2.0f * (qy * qz - qw * qx);
    float r20 = 2.0f * (qx * qz - qw * qy);
    float r21 = 2.0f * (qy * qz + qw * qx);
    float r22 = 1.0f - 2.0f * (qx * qx + qy * qy);
    const float k = 0.84932180028801904f;
    float k0 = k / s0, k1 = k / s1, k2 = k / s2;
    float m00 = k0 * r00, m01 = k0 * r10, m02 = k0 * r20;
    float m10 = k1 * r01, m11 = k1 * r11, m12 = k1 * r21;
    float m20 = k2 * r02, m21 = k2 * r12, m22 = k2 * r22;
    float mx = xyz[3 * g + 0], my = xyz[3 * g + 1], mz = xyz[3 * g + 2];
    float wv = sigmoidf(weight[g]) * sigmoidf(values[g]);
    float* c = ws + OFF_PAR + (size_t)g * 16;
    c[0] = m00; c[1] = m01; c[2] = m02;
    c[3] = m10; c[4] = m11; c[5] = m12;
    c[6] = m20; c[7] = m21; c[8] = m22;
    c[9]  = -(m00 * mx + m01 * my + m02 * mz);
    c[10] = -(m10 * mx + m11 * my + m12 * mz);
    c[11] = -(m20 * mx + m21 * my + m22 * mz);
    c[12] = log2f(wv);
    c[13] = 0.0f; c[14] = 0.0f; c[15] = 0.0f;
}

#define GAUSS_REC4(r0, r1, r2, r3)                                            \
    GPOINT(r0, r1, r2, r3, X0, Y0, Z0, acc0);                                 \
    GPOINT(r0, r1, r2, r3, X1, Y1, Z1, acc1);                                 \
    GPOINT(r0, r1, r2, r3, X2, Y2, Z2, acc2);                                 \
    GPOINT(r0, r1, r2, r3, X3, Y3, Z3, acc3);

__global__ __launch_bounds__(256) void eval_kernel(
        const float* __restrict__ x,
        const float* __restrict__ ws,
        const void* __restrict__ inside,
        float* __restrict__ out) {
    __shared__ float4 spbuf[1028];
    const float* params = ws + OFF_PAR;
    const int mode = ((const int*)ws)[OFF_FLAG];
    const int tid = threadIdx.x, lane = tid & 63, w = tid >> 6;
    const int segq = blockIdx.x & 7, pg = blockIdx.x >> 3;

    const float4* src = (const float4*)(params + (size_t)segq * 256 * 16);
#pragma unroll
    for (int i = 0; i < 4; ++i) spbuf[tid + 256 * i] = src[tid + 256 * i];
    if (tid < 4) spbuf[1024 + tid] = src[1024 + tid];

    const int p0 = pg * 256 + lane;
    float X0 = (x[3 * (p0 + 0) + 0] + 1.0f) * 0.5f;
    float Y0 = (x[3 * (p0 + 0) + 1] + 1.0f) * 0.5f;
    float Z0 = (x[3 * (p0 + 0) + 2] + 1.0f) * 0.5f;
    float X1 = (x[3 * (p0 + 64) + 0] + 1.0f) * 0.5f;
    float Y1 = (x[3 * (p0 + 64) + 1] + 1.0f) * 0.5f;
    float Z1 = (x[3 * (p0 + 64) + 2] + 1.0f) * 0.5f;
    float X2 = (x[3 * (p0 + 128) + 0] + 1.0f) * 0.5f;
    float Y2 = (x[3 * (p0 + 128) + 1] + 1.0f) * 0.5f;
    float Z2 = (x[3 * (p0 + 128) + 2] + 1.0f) * 0.5f;
    float X3 = (x[3 * (p0 + 192) + 0] + 1.0f) * 0.5f;
    float Y3 = (x[3 * (p0 + 192) + 1] + 1.0f) * 0.5f;
    float Z3 = (x[3 * (p0 + 192) + 2] + 1.0f) * 0.5f;
    __syncthreads();

    const float4* sp = spbuf + (size_t)w * 256;
    float acc0 = 0, acc1 = 0, acc2 = 0, acc3 = 0;
    float4 A0 = sp[0], A1 = sp[1], A2 = sp[2], A3 = sp[3];
    float4 B0, B1, B2, B3;
#pragma unroll 1
    for (int g = 0; g < 64; g += 2) {
        const float4* qq = sp + (size_t)(g + 1) * 4;
        B0 = qq[0]; B1 = qq[1]; B2 = qq[2]; B3 = qq[3];
        GAUSS_REC4(A0, A1, A2, A3);
        qq = sp + (size_t)(g + 2) * 4;
        A0 = qq[0]; A1 = qq[1]; A2 = qq[2]; A3 = qq[3];
        GAUSS_REC4(B0, B1, B2, B3);
    }
    __syncthreads();
    float* part = (float*)spbuf;
    part[w * 256 + 0 + lane] = acc0;
    part[w * 256 + 64 + lane] = acc1;
    part[w * 256 + 128 + lane] = acc2;
    part[w * 256 + 192 + lane] = acc3;
    __syncthreads();
    float y = part[tid] + part[256 + tid] + part[512 + tid] + part[768 + tid];
    int p = pg * 256 + tid;
    bool m = mode ? (((const uint8_t*)inside)[p] != 0)
                  : (((const int*)inside)[p] != 0);
    if (m) atomicAdd(&out[p], y);
}

extern "C" void kernel_launch(void* const* d_in, const int* in_sizes, int n_in,
                              void* d_out, int out_size, void* d_ws, size_t ws_size,
                              hipStream_t stream) {
    const float* x        = (const float*)d_in[0];
    const float* xyz      = (const float*)d_in[1];
    const float* weight   = (const float*)d_in[2];
    const float* scaling  = (const float*)d_in[3];
    const float* rotation = (const float*)d_in[4];
    const float* values   = (const float*)d_in[5];
    const void*  inside   = d_in[6];

    float* ws = (float*)d_ws;

    if (ws_size >= NEED_FLOATS * 4) {
        prep_kernel<<<SCAT_B + 5, 512, 0, stream>>>(
            x, xyz, weight, scaling, rotation, values,
            (const uint8_t*)inside, ws);
        eval_cell_kernel<<<NCELL, 512, 0, stream>>>(
            ws, inside, (float*)d_out);
    } else if (ws_size >= (size_t)(256 + (G_N + 2) * 16 * 4)) {
        zero_out_kernel<<<P_N / 256, 256, 0, stream>>>((float*)d_out);
        precompute_kernel<<<9, 256, 0, stream>>>(
            xyz, weight, scaling, rotation, values, (const uint8_t*)inside, ws);
        eval_kernel<<<(P_N / 256) * 8, 256, 0, stream>>>(
            x, ws, inside, (float*)d_out);
    }
}